// Round 1
// baseline (308.383 us; speedup 1.0000x reference)
//
#include <hip/hip_runtime.h>

// GraphConvolution: out = segment_sum(edge_val * support[edge_col], edge_row) * GAMMA + x_0 + bias
// where support = x @ cayley(W). Algebraic identity: cayley as written in the
// reference is solve(I+s, (I-s)^T)^T with s skew-symmetric => (I-s)^T = I+s
// => ortho_weight == I exactly. So support == x and the GEMM is skipped.
// GAMMA == 1.0 (compile-time constant in reference).

#define DFEAT 64

// out = x_0 + bias  (vectorized float4; D=64 divisible by 4 so no bias wrap)
__global__ void init_out_kernel(const float* __restrict__ x0,
                                const float* __restrict__ bias,
                                float* __restrict__ out, int n4) {
    int i = blockIdx.x * blockDim.x + threadIdx.x;
    if (i < n4) {
        float4 v = ((const float4*)x0)[i];
        int d = (i * 4) & (DFEAT - 1);
        v.x += bias[d + 0];
        v.y += bias[d + 1];
        v.z += bias[d + 2];
        v.w += bias[d + 3];
        ((float4*)out)[i] = v;
    }
}

// One 64-lane wave per edge; lane d owns feature d.
// Gather x[col,:] (256B coalesced), scatter-add into out[row,:].
__global__ void edge_scatter_kernel(const float* __restrict__ x,
                                    const float* __restrict__ edge_val,
                                    const int* __restrict__ edge_row,
                                    const int* __restrict__ edge_col,
                                    float* __restrict__ out, int E) {
    int tid = blockIdx.x * blockDim.x + threadIdx.x;
    int wave = tid >> 6;
    int lane = tid & 63;
    int nwaves = (gridDim.x * blockDim.x) >> 6;
    for (int e = wave; e < E; e += nwaves) {
        int row = edge_row[e];   // same addr across wave -> broadcast load
        int col = edge_col[e];
        float val = edge_val[e];
        float xv = x[col * DFEAT + lane];
        atomicAdd(&out[row * DFEAT + lane], val * xv);
    }
}

extern "C" void kernel_launch(void* const* d_in, const int* in_sizes, int n_in,
                              void* d_out, int out_size, void* d_ws, size_t ws_size,
                              hipStream_t stream) {
    const float* x    = (const float*)d_in[0];
    const float* x0   = (const float*)d_in[1];
    const float* ev   = (const float*)d_in[2];
    // d_in[3] = weight: unused — Cayley transform as written is exactly identity.
    const float* bias = (const float*)d_in[4];
    const int*   er   = (const int*)d_in[5];
    const int*   ec   = (const int*)d_in[6];
    float* out = (float*)d_out;

    int E     = in_sizes[2];
    int total = out_size;        // N * D
    int n4    = total / 4;

    init_out_kernel<<<(n4 + 255) / 256, 256, 0, stream>>>(x0, bias, out, n4);

    // 8192 blocks x 256 threads = 32768 waves; ~32 edges per wave via stride loop.
    edge_scatter_kernel<<<8192, 256, 0, stream>>>(x, ev, er, ec, out, E);
}